// Round 8
// baseline (304.979 us; speedup 1.0000x reference)
//
#include <hip/hip_runtime.h>

#define FD 128            // feature dim
#define HD 64             // hidden per MLP
#define NC 128            // combined cols (64 MLP-a | 64 MLP-n)

typedef __attribute__((ext_vector_type(8))) short bf16x8;
typedef __attribute__((ext_vector_type(4))) float f32x4;

__device__ __forceinline__ unsigned bfr(float x) {
    unsigned u = __float_as_uint(x);
    return (u + 0x7fffu + ((u >> 16) & 1u)) >> 16;
}

// Fold LN affine into first-layer weights (bf16, transposed); LN bias into layer bias.
__global__ void prep_kernel(
    const float* __restrict__ lnag, const float* __restrict__ lnab,
    const float* __restrict__ Wa1, const float* __restrict__ ba1, const float* __restrict__ Wa2,
    const float* __restrict__ lnng, const float* __restrict__ lnnb,
    const float* __restrict__ Wn1, const float* __restrict__ bn1, const float* __restrict__ Wn2,
    unsigned short* __restrict__ wq, float* __restrict__ c, float* __restrict__ w2)
{
    int n = threadIdx.x;  // 0..127
    const float* W  = (n < HD) ? Wa1 : Wn1;
    const float* g  = (n < HD) ? lnag : lnng;
    const float* bb = (n < HD) ? lnab : lnnb;
    const float* b1 = (n < HD) ? ba1 : bn1;
    const float* W2 = (n < HD) ? Wa2 : Wn2;
    int h = n & (HD - 1);
    float accb = b1[h];
    for (int f = 0; f < FD; ++f) {
        float w = W[f * HD + h];
        wq[n * FD + f] = (unsigned short)bfr(g[f] * w);
        accb += bb[f] * w;
    }
    c[n] = accb;
    w2[n] = W2[h];
}

// Thin streaming kernel: t[n] = sum_{d,f} vec[n,d,f]*wnu[f]*(pos[n,d]-mc[b,d]).
// 2 nodes per wave (32 lanes each), 3 float4 HBM loads per lane, 5-shfl reduce.
// Forced <=64 VGPR -> 32 waves/CU: load issue never starves.
__global__ __launch_bounds__(256, 8) void vec_kernel(
    const float* __restrict__ vec, const float* __restrict__ wnu,
    const float* __restrict__ pos, const float* __restrict__ mc,
    const int* __restrict__ bidx, float* __restrict__ t, int n_nodes)
{
    int gid = (int)(blockIdx.x * blockDim.x + threadIdx.x);
    int wave = gid >> 6;
    int lane = threadIdx.x & 63;
    int h = lane >> 5, j = lane & 31;
    int node = wave * 2 + h;
    bool valid = node < n_nodes;
    int n = valid ? node : (n_nodes - 1);
    const float4* vr = reinterpret_cast<const float4*>(vec + (size_t)n * 3 * FD);
    float4 v0 = vr[j], v1 = vr[32 + j], v2 = vr[64 + j];
    float4 wn = reinterpret_cast<const float4*>(wnu)[j];
    int b = bidx[n];
    float m0 = pos[n * 3 + 0] - mc[b * 3 + 0];
    float m1 = pos[n * 3 + 1] - mc[b * 3 + 1];
    float m2 = pos[n * 3 + 2] - mc[b * 3 + 2];
    float acc = (v0.x * wn.x + v0.y * wn.y + v0.z * wn.z + v0.w * wn.w) * m0
              + (v1.x * wn.x + v1.y * wn.y + v1.z * wn.z + v1.w * wn.w) * m1
              + (v2.x * wn.x + v2.y * wn.y + v2.z * wn.z + v2.w * wn.w) * m2;
#pragma unroll
    for (int off = 16; off; off >>= 1) acc += __shfl_xor(acc, off);
    if (j == 0 && valid) t[node] = acc;
}

// Barrier-free, LDS-free MLP: each wave owns 16 nodes end-to-end.
// Lane loads exactly its MFMA A-fragment floats of row lane&15; LN via shfl_xor(16,32);
// bf16 pack in-register; [16x128]@[128x128] MFMA with B-frags from L1/L2-resident wq;
// SiLU + second-layer dot + butterfly + atomic scatter (t read from global).
__global__ __launch_bounds__(256, 4) void mlp_kernel(
    const float* __restrict__ scaler, const float* __restrict__ t,
    const int* __restrict__ bidx,
    const unsigned short* __restrict__ wq, const float* __restrict__ c,
    const float* __restrict__ w2, const float* __restrict__ ba2,
    const float* __restrict__ bn2, float* __restrict__ out, int n_nodes)
{
    int tid = threadIdx.x;
    int lane = tid & 63, w = tid >> 6;
    int rowbase = blockIdx.x * 64 + w * 16;   // this wave's 16 nodes
    int lrow = lane & 15, lgrp = lane >> 4;

    int xnode = rowbase + lrow;
    int gx = xnode < n_nodes ? xnode : (n_nodes - 1);
    const float4* xp = reinterpret_cast<const float4*>(scaler + (size_t)gx * FD);
    float4 xv[8];
#pragma unroll
    for (int ks = 0; ks < 4; ++ks) {
        xv[2 * ks]     = xp[ks * 8 + lgrp * 2];
        xv[2 * ks + 1] = xp[ks * 8 + lgrp * 2 + 1];
    }

    float s = 0.f, s2 = 0.f;
#pragma unroll
    for (int i = 0; i < 8; ++i) {
        float4 v = xv[i];
        s  += v.x + v.y + v.z + v.w;
        s2 += v.x * v.x + v.y * v.y + v.z * v.z + v.w * v.w;
    }
    s  += __shfl_xor(s, 16);  s  += __shfl_xor(s, 32);
    s2 += __shfl_xor(s2, 16); s2 += __shfl_xor(s2, 32);
    float mu = s * (1.f / FD);
    float var = s2 * (1.f / FD) - mu * mu;
    float rstd = rsqrtf(var + 1e-5f);

    bf16x8 af[4];
#pragma unroll
    for (int ks = 0; ks < 4; ++ks) {
        float4 a = xv[2 * ks], b = xv[2 * ks + 1];
        union { unsigned u[4]; bf16x8 v; } pk;
        pk.u[0] = bfr((a.x - mu) * rstd) | (bfr((a.y - mu) * rstd) << 16);
        pk.u[1] = bfr((a.z - mu) * rstd) | (bfr((a.w - mu) * rstd) << 16);
        pk.u[2] = bfr((b.x - mu) * rstd) | (bfr((b.y - mu) * rstd) << 16);
        pk.u[3] = bfr((b.z - mu) * rstd) | (bfr((b.w - mu) * rstd) << 16);
        af[ks] = pk.v;
    }

    float pa[4] = {0.f, 0.f, 0.f, 0.f}, pn[4] = {0.f, 0.f, 0.f, 0.f};
#pragma unroll
    for (int tile = 0; tile < 8; ++tile) {
        f32x4 acc = {0.f, 0.f, 0.f, 0.f};
        int n = tile * 16 + lrow;
        const bf16x8* brow = reinterpret_cast<const bf16x8*>(wq + n * FD);
#pragma unroll
        for (int ks = 0; ks < 4; ++ks) {
            bf16x8 bf = brow[ks * 4 + lgrp];
            acc = __builtin_amdgcn_mfma_f32_16x16x32_bf16(af[ks], bf, acc, 0, 0, 0);
        }
        int col = tile * 16 + lrow;
        float bias = c[col], w2v = w2[col];
#pragma unroll
        for (int r = 0; r < 4; ++r) {
            float h1 = acc[r] + bias;
            float y = h1 / (1.f + __expf(-h1));
            float cb = y * w2v;
            if (tile < 4) pa[r] += cb; else pn[r] += cb;
        }
    }
#pragma unroll
    for (int off = 1; off < 16; off <<= 1) {
#pragma unroll
        for (int r = 0; r < 4; ++r) {
            pa[r] += __shfl_xor(pa[r], off);
            pn[r] += __shfl_xor(pn[r], off);
        }
    }
    if (lrow == 0) {
        float b2a = ba2[0], b2n = bn2[0];
#pragma unroll
        for (int r = 0; r < 4; ++r) {
            int node = rowbase + lgrp * 4 + r;
            if (node < n_nodes) {
                float val = (pa[r] + b2a) + (2.f / 3.f) * (pn[r] + b2n) * t[node];
                atomicAdd(out + bidx[node], val);
            }
        }
    }
}

extern "C" void kernel_launch(void* const* d_in, const int* in_sizes, int n_in,
                              void* d_out, int out_size, void* d_ws, size_t ws_size,
                              hipStream_t stream) {
    const float* pos    = (const float*)d_in[0];
    const float* mc     = (const float*)d_in[1];
    const float* scaler = (const float*)d_in[2];
    const float* vec    = (const float*)d_in[3];
    const int*   bidx   = (const int*)d_in[4];
    const float* lnag   = (const float*)d_in[5];
    const float* lnab   = (const float*)d_in[6];
    const float* Wa1    = (const float*)d_in[7];
    const float* ba1    = (const float*)d_in[8];
    const float* Wa2    = (const float*)d_in[9];
    const float* ba2    = (const float*)d_in[10];
    const float* lnng   = (const float*)d_in[11];
    const float* lnnb   = (const float*)d_in[12];
    const float* Wn1    = (const float*)d_in[13];
    const float* bn1    = (const float*)d_in[14];
    const float* Wn2    = (const float*)d_in[15];
    const float* bn2    = (const float*)d_in[16];
    const float* Wnu    = (const float*)d_in[17];

    int N = in_sizes[0] / 3;
    int B = in_sizes[1] / 3;

    unsigned short* wq = (unsigned short*)d_ws;            // NC*FD bf16 = 32 KiB
    float* c  = (float*)((char*)d_ws + NC * FD * 2);       // 128 f32
    float* w2 = c + NC;                                    // 128 f32
    float* t  = w2 + NC;                                   // N f32

    hipMemsetAsync(d_out, 0, (size_t)B * sizeof(float), stream);

    hipLaunchKernelGGL(prep_kernel, dim3(1), dim3(NC), 0, stream,
                       lnag, lnab, Wa1, ba1, Wa2, lnng, lnnb, Wn1, bn1, Wn2, wq, c, w2);

    int vblocks = (N + 7) / 8;   // 8 nodes per 256-thread block
    hipLaunchKernelGGL(vec_kernel, dim3(vblocks), dim3(256), 0, stream,
                       vec, Wnu, pos, mc, bidx, t, N);

    int mblocks = (N + 63) / 64; // 64 nodes per 256-thread block
    hipLaunchKernelGGL(mlp_kernel, dim3(mblocks), dim3(256), 0, stream,
                       scaler, t, bidx, wq, c, w2, ba2, bn2, (float*)d_out, N);
}